// Round 3
// baseline (434.465 us; speedup 1.0000x reference)
//
#include <hip/hip_runtime.h>

// Problem constants (fixed by reference)
#define NAG   16
#define OBSD  256
#define ACTD  32
#define SCF   16
#define H1D   128
#define H2D   64
#define BT    1024          // B*T
#define NTOK  16384         // BT*NAG
#define CFS   32768         // BT*ACTD, stride of one cf sample slab

typedef float f4 __attribute__((ext_vector_type(4)));

// LDS float offsets (total 10240 floats = 40 KB -> 4 blocks/CU)
#define HS_OFF   0          // h1: 32 x 128, XOR-swizzled
#define H2S_OFF  4096       // h2: 32 x 64,  XOR-swizzled
#define W2S_OFF  6144       // W2 K-half: 64 x 64
// prologue obs tile occupies [0, 8192) before the loop starts

// ws float offsets
#define WS_PW   0           // p_with   [16384 x 32]
#define WS_PQ0  524288      // partial p_without sum, chunk 0
#define WS_PQ1  1048576     // partial p_without sum, chunk 1

// ---------------------------------------------------------------------------
// Fused kernel. grid = 512 token-tiles x 2 eval-chunks.
// chunk 0: evals {with, cf s=0..7};  chunk 1: {zero, cf s=8..15}.
// Per block: prologue computes hobs = obs@W1[0:256]+b1 in regs (tile 4x4),
// then 9 evals: h1=relu(hobs+act@W1a); h2=relu(h1@W2+b2); p=h2@W3+b3.
// ---------------------------------------------------------------------------
__global__ __launch_bounds__(256, 4) void k_fused(
    const float* __restrict__ obs, const float* __restrict__ actions,
    const float* __restrict__ cf, const float* __restrict__ W1,
    const float* __restrict__ b1, const float* __restrict__ W2,
    const float* __restrict__ b2v, const float* __restrict__ W3,
    const float* __restrict__ b3v, float* __restrict__ ws)
{
    __shared__ float lds[10240];

    const int tid   = threadIdx.x;
    const int chunk = blockIdx.x & 1;
    const int g0    = (blockIdx.x >> 1) * 32;

    const int rb1 = tid >> 5, cb1 = tid & 31;   // GEMM1/obs: 4 tok x 4 col
    const int rb2 = tid >> 4, cb2 = tid & 15;   // GEMM2: 2 tok x 4 col
    const int r3  = tid >> 3, cb3 = tid & 7;    // GEMM3: 1 tok x 4 col

    // ---- prologue: stage obs tile 32x256 (8192 floats = 2048 f4) ----
    {
        const float* src = obs + g0 * OBSD;
        #pragma unroll
        for (int j = 0; j < 8; ++j) {
            int idx = tid + j * 256;                    // f4 index
            *(f4*)(lds + idx * 4) = *(const f4*)(src + idx * 4);
        }
    }
    __syncthreads();

    // ---- obs-GEMM: hobs = obs @ W1[0:256,:] + b1 (B streamed from L2) ----
    f4 hobs[4];
    {
        float acc[4][4] = {};
        #pragma unroll 8
        for (int k = 0; k < OBSD; k += 4) {
            f4 a[4], b[4];
            #pragma unroll
            for (int i = 0; i < 4; ++i)
                a[i] = *(const f4*)(lds + (rb1 * 4 + i) * OBSD + k);
            #pragma unroll
            for (int kk = 0; kk < 4; ++kk)
                b[kk] = *(const f4*)(W1 + (k + kk) * H1D + cb1 * 4);
            #pragma unroll
            for (int i = 0; i < 4; ++i)
                #pragma unroll
                for (int kk = 0; kk < 4; ++kk)
                    #pragma unroll
                    for (int j = 0; j < 4; ++j)
                        acc[i][j] = fmaf(a[i][kk], b[kk][j], acc[i][j]);
        }
        f4 bias = *(const f4*)(b1 + cb1 * 4);
        #pragma unroll
        for (int i = 0; i < 4; ++i)
            #pragma unroll
            for (int j = 0; j < 4; ++j)
                hobs[i][j] = acc[i][j] + bias[j];
    }
    __syncthreads();   // obs region about to be overwritten (Hs/W2s)

    // per-thread act addressing for GEMM1-A (4 tokens)
    int aoff[4], cfoff[4];
    #pragma unroll
    for (int i = 0; i < 4; ++i) {
        int tg = g0 + rb1 * 4 + i;
        aoff[i]  = tg * ACTD;
        cfoff[i] = ((tg & (NAG - 1)) * SCF * BT + (tg >> 4)) * ACTD;
    }
    const float* W1a = W1 + OBSD * H1D;
    f4 bias2 = *(const f4*)(b2v + cb2 * 4);
    f4 bias3 = *(const f4*)(b3v + cb3 * 4);

    f4 pw = {0.f, 0.f, 0.f, 0.f};
    f4 pq = {0.f, 0.f, 0.f, 0.f};

    const int xt1[4] = { ((rb1*4+0)&7)<<2, ((rb1*4+1)&7)<<2,
                         ((rb1*4+2)&7)<<2, ((rb1*4+3)&7)<<2 };
    const int t20 = rb2 * 2, t21 = rb2 * 2 + 1;
    const int x20 = (t20 & 7) << 2, x21 = (t21 & 7) << 2;
    const int x3  = (r3 & 7) << 2;

    for (int ee = 0; ee < 9; ++ee) {
        const bool zeroEval = (chunk == 1) && (ee == 0);
        const bool withEval = (chunk == 0) && (ee == 0);
        const int  s        = (chunk == 0) ? (ee - 1) : (ee + 7);

        // --- s1: GEMM1 from global (acts broadcast + W1a via L1) -> hval ---
        f4 hv[4];
        if (!zeroEval) {
            const float* ap[4];
            #pragma unroll
            for (int i = 0; i < 4; ++i)
                ap[i] = withEval ? (actions + aoff[i]) : (cf + cfoff[i] + s * CFS);
            float acc[4][4] = {};
            #pragma unroll
            for (int k = 0; k < ACTD; k += 4) {
                f4 a[4], b[4];
                #pragma unroll
                for (int i = 0; i < 4; ++i) a[i] = *(const f4*)(ap[i] + k);
                #pragma unroll
                for (int kk = 0; kk < 4; ++kk)
                    b[kk] = *(const f4*)(W1a + (k + kk) * H1D + cb1 * 4);
                #pragma unroll
                for (int i = 0; i < 4; ++i)
                    #pragma unroll
                    for (int kk = 0; kk < 4; ++kk)
                        #pragma unroll
                        for (int j = 0; j < 4; ++j)
                            acc[i][j] = fmaf(a[i][kk], b[kk][j], acc[i][j]);
            }
            #pragma unroll
            for (int i = 0; i < 4; ++i)
                #pragma unroll
                for (int j = 0; j < 4; ++j)
                    hv[i][j] = fmaxf(hobs[i][j] + acc[i][j], 0.f);
        } else {
            #pragma unroll
            for (int i = 0; i < 4; ++i)
                #pragma unroll
                for (int j = 0; j < 4; ++j)
                    hv[i][j] = fmaxf(hobs[i][j], 0.f);
        }

        // --- s2: stage W2 half 0 (rows 0..63) ---
        #pragma unroll
        for (int j = 0; j < 4; ++j)
            *(f4*)(lds + W2S_OFF + tid * 4 + j * 1024) =
                *(const f4*)(W2 + tid * 4 + j * 1024);

        // --- s3: write Hs (XOR-swizzled rows) ---
        #pragma unroll
        for (int i = 0; i < 4; ++i) {
            int t = rb1 * 4 + i;
            *(f4*)(lds + HS_OFF + t * H1D + ((cb1 * 4) ^ xt1[i])) = hv[i];
        }
        __syncthreads();   // B1

        // --- s5: GEMM2 K-half 0 ---
        float acc2[2][4] = {};
        #pragma unroll 8
        for (int k = 0; k < 64; k += 4) {
            f4 a0 = *(const f4*)(lds + HS_OFF + t20 * H1D + (k ^ x20));
            f4 a1 = *(const f4*)(lds + HS_OFF + t21 * H1D + (k ^ x21));
            f4 b[4];
            #pragma unroll
            for (int kk = 0; kk < 4; ++kk)
                b[kk] = *(const f4*)(lds + W2S_OFF + (k + kk) * H2D + cb2 * 4);
            #pragma unroll
            for (int kk = 0; kk < 4; ++kk)
                #pragma unroll
                for (int j = 0; j < 4; ++j) {
                    acc2[0][j] = fmaf(a0[kk], b[kk][j], acc2[0][j]);
                    acc2[1][j] = fmaf(a1[kk], b[kk][j], acc2[1][j]);
                }
        }
        __syncthreads();   // B2 (W2s about to be restaged)

        // --- s7: stage W2 half 1 (rows 64..127) ---
        #pragma unroll
        for (int j = 0; j < 4; ++j)
            *(f4*)(lds + W2S_OFF + tid * 4 + j * 1024) =
                *(const f4*)(W2 + 4096 + tid * 4 + j * 1024);
        __syncthreads();   // B3

        // --- s9: GEMM2 K-half 1, relu, write H2s ---
        #pragma unroll 8
        for (int k = 0; k < 64; k += 4) {
            f4 a0 = *(const f4*)(lds + HS_OFF + t20 * H1D + ((64 + k) ^ x20));
            f4 a1 = *(const f4*)(lds + HS_OFF + t21 * H1D + ((64 + k) ^ x21));
            f4 b[4];
            #pragma unroll
            for (int kk = 0; kk < 4; ++kk)
                b[kk] = *(const f4*)(lds + W2S_OFF + (k + kk) * H2D + cb2 * 4);
            #pragma unroll
            for (int kk = 0; kk < 4; ++kk)
                #pragma unroll
                for (int j = 0; j < 4; ++j) {
                    acc2[0][j] = fmaf(a0[kk], b[kk][j], acc2[0][j]);
                    acc2[1][j] = fmaf(a1[kk], b[kk][j], acc2[1][j]);
                }
        }
        {
            f4 v0, v1;
            #pragma unroll
            for (int j = 0; j < 4; ++j) {
                v0[j] = fmaxf(acc2[0][j] + bias2[j], 0.f);
                v1[j] = fmaxf(acc2[1][j] + bias2[j], 0.f);
            }
            *(f4*)(lds + H2S_OFF + t20 * H2D + ((cb2 * 4) ^ x20)) = v0;
            *(f4*)(lds + H2S_OFF + t21 * H2D + ((cb2 * 4) ^ x21)) = v1;
        }
        __syncthreads();   // B4

        // --- s11: GEMM3 (W3 via L1) -> accumulate pw / pq ---
        {
            f4 acc = {0.f, 0.f, 0.f, 0.f};
            #pragma unroll 8
            for (int k = 0; k < H2D; k += 4) {
                f4 a = *(const f4*)(lds + H2S_OFF + r3 * H2D + (k ^ x3));
                #pragma unroll
                for (int kk = 0; kk < 4; ++kk) {
                    f4 b = *(const f4*)(W3 + (k + kk) * ACTD + cb3 * 4);
                    #pragma unroll
                    for (int j = 0; j < 4; ++j)
                        acc[j] = fmaf(a[kk], b[j], acc[j]);
                }
            }
            #pragma unroll
            for (int j = 0; j < 4; ++j) acc[j] += bias3[j];
            if (withEval) pw = acc;
            else {
                #pragma unroll
                for (int j = 0; j < 4; ++j) pq[j] += acc[j];
            }
        }
        // next eval's W2/Hs writes are ordered by B4 + B1
    }

    // ---- epilogue: write partial logits to ws ----
    const int gg = g0 + r3;
    if (chunk == 0) {
        *(f4*)(ws + WS_PW  + gg * ACTD + cb3 * 4) = pw;
        *(f4*)(ws + WS_PQ0 + gg * ACTD + cb3 * 4) = pq;
    } else {
        *(f4*)(ws + WS_PQ1 + gg * ACTD + cb3 * 4) = pq;
    }
}

// ---------------------------------------------------------------------------
// Combine + KL kernel: 8 threads per token.
// ---------------------------------------------------------------------------
__global__ __launch_bounds__(256) void k_kl(
    const float* __restrict__ ws, float* __restrict__ out)
{
    const int tid = threadIdx.x;
    const int gg  = blockIdx.x * 32 + (tid >> 3);
    const int cb3 = tid & 7;

    f4 pw  = *(const f4*)(ws + WS_PW  + gg * ACTD + cb3 * 4);
    f4 pa  = *(const f4*)(ws + WS_PQ0 + gg * ACTD + cb3 * 4);
    f4 pb  = *(const f4*)(ws + WS_PQ1 + gg * ACTD + cb3 * 4);

    const float inv17 = 1.0f / 17.0f;
    f4 qv;
    #pragma unroll
    for (int j = 0; j < 4; ++j) qv[j] = (pa[j] + pb[j]) * inv17;

    float mw = fmaxf(fmaxf(pw[0], pw[1]), fmaxf(pw[2], pw[3]));
    float mq = fmaxf(fmaxf(qv[0], qv[1]), fmaxf(qv[2], qv[3]));
    #pragma unroll
    for (int m = 1; m < 8; m <<= 1) {
        mw = fmaxf(mw, __shfl_xor(mw, m));
        mq = fmaxf(mq, __shfl_xor(mq, m));
    }
    float sw = 0.f, sq = 0.f;
    #pragma unroll
    for (int j = 0; j < 4; ++j) {
        sw += expf(pw[j] - mw);
        sq += expf(qv[j] - mq);
    }
    #pragma unroll
    for (int m = 1; m < 8; m <<= 1) {
        sw += __shfl_xor(sw, m);
        sq += __shfl_xor(sq, m);
    }
    const float lsw = logf(sw), lsq = logf(sq);
    float kl = 0.f;
    #pragma unroll
    for (int j = 0; j < 4; ++j) {
        float lq = qv[j] - mq - lsq;
        float lp = pw[j] - mw - lsw;
        kl += expf(lq) * (lq - lp);
    }
    #pragma unroll
    for (int m = 1; m < 8; m <<= 1) kl += __shfl_xor(kl, m);

    if (cb3 == 0) out[gg] = kl * (1.0f / 32.0f);
}

// ---------------------------------------------------------------------------
extern "C" void kernel_launch(void* const* d_in, const int* in_sizes, int n_in,
                              void* d_out, int out_size, void* d_ws, size_t ws_size,
                              hipStream_t stream)
{
    const float* obs     = (const float*)d_in[0];
    const float* actions = (const float*)d_in[1];
    const float* cf      = (const float*)d_in[2];
    const float* W1      = (const float*)d_in[3];
    const float* b1      = (const float*)d_in[4];
    const float* W2      = (const float*)d_in[5];
    const float* b2      = (const float*)d_in[6];
    const float* W3      = (const float*)d_in[7];
    const float* b3      = (const float*)d_in[8];
    float* outp = (float*)d_out;
    float* ws   = (float*)d_ws;    // 3 x 2 MB logit buffers

    k_fused<<<(NTOK / 32) * 2, 256, 0, stream>>>(obs, actions, cf, W1, b1, W2,
                                                 b2, W3, b3, ws);
    k_kl  <<<NTOK / 32, 256, 0, stream>>>(ws, outp);
}

// Round 5
// 265.062 us; speedup vs baseline: 1.6391x; 1.6391x over previous
//
#include <hip/hip_runtime.h>

// Problem constants (fixed by reference)
#define NAG   16
#define OBSD  256
#define ACTD  32
#define SCF   16
#define H1D   128
#define H2D   64
#define BT    1024          // B*T
#define NTOK  16384         // BT*NAG
#define CFS   32768         // BT*ACTD stride of one cf sample slab
#define NEVAL 18

typedef float f4 __attribute__((ext_vector_type(4)));

// ---- LDS float-offset map (union of prologue / main phases) ----
// prologue: OBS [0,8192) 32x256 ; BS [8192,12288) 32x128
// main:     Acts [0,1152) 32x36 ; W1s [1152,5248) 32x128 ;
//           W2s [5248,13440) 128x64 ; Hs [13440,17664) 32x132 ;
//           H2s [17664,19840) 32x68
#define OBS_OFF  0
#define BS_OFF   8192
#define ACT_OFF  0
#define W1S_OFF  1152
#define W2S_OFF  5248
#define HS_OFF   13440
#define H2S_OFF  17664
#define LDS_FLOATS 19840     // 79360 B -> 2 blocks/CU

// ---------------------------------------------------------------------------
// Single fused kernel: 32 tokens/block, grid 512.
// Prologue: hobs = obs @ W1[0:256,:] + b1 (LDS-staged tiles, result in regs).
// Loop e=0..17: h1=relu(hobs + act_e @ W1a); h2=relu(h1@W2+b2); p=h2@W3+b3.
//   e==0 -> p_with ; e==1 zero action ; e>=2 cf samples. Accumulate p_without.
// Epilogue: KL(softmax(p_wo) || log_softmax(p_with)) mean over 32 -> out[g].
// ---------------------------------------------------------------------------
__global__ __launch_bounds__(256, 2) void k_fused(
    const float* __restrict__ obs, const float* __restrict__ actions,
    const float* __restrict__ cf, const float* __restrict__ W1,
    const float* __restrict__ b1, const float* __restrict__ W2,
    const float* __restrict__ b2v, const float* __restrict__ W3,
    const float* __restrict__ b3v, float* __restrict__ out)
{
    __shared__ float lds[LDS_FLOATS];

    const int tid = threadIdx.x;
    const int g0  = blockIdx.x * 32;

    const int rb1 = tid >> 5, cb1 = tid & 31;   // GEMM1/obs: 4 tok x 4 col
    const int rb2 = tid >> 4, cb2 = tid & 15;   // GEMM2: 2 tok x 4 col
    const int r3  = tid >> 3, cb3 = tid & 7;    // GEMM3: 1 tok x 4 col

    // ================= prologue: obs-GEMM -> hobs regs =================
    // stage obs tile 32x256 (2048 f4, coalesced)
    {
        const float* src = obs + g0 * OBSD;
        #pragma unroll
        for (int j = 0; j < 8; ++j) {
            int idx = tid + j * 256;
            *(f4*)(lds + OBS_OFF + idx * 4) = *(const f4*)(src + idx * 4);
        }
    }

    float acc[4][4] = {};
    for (int kt = 0; kt < OBSD; kt += 32) {
        // stage W1 rows kt..kt+31 (4096 floats, coalesced)
        __syncthreads();
        const float* wsrc = W1 + kt * H1D;
        #pragma unroll
        for (int u = 0; u < 4; ++u)
            *(f4*)(lds + BS_OFF + u * 1024 + tid * 4) =
                *(const f4*)(wsrc + u * 1024 + tid * 4);
        __syncthreads();
        #pragma unroll
        for (int k0 = 0; k0 < 32; k0 += 4) {
            f4 a[4], b[4];
            #pragma unroll
            for (int i = 0; i < 4; ++i)
                a[i] = *(const f4*)(lds + OBS_OFF + (rb1 * 4 + i) * OBSD + kt + k0);
            #pragma unroll
            for (int kk = 0; kk < 4; ++kk)
                b[kk] = *(const f4*)(lds + BS_OFF + (k0 + kk) * H1D + cb1 * 4);
            #pragma unroll
            for (int i = 0; i < 4; ++i)
                #pragma unroll
                for (int kk = 0; kk < 4; ++kk)
                    #pragma unroll
                    for (int j = 0; j < 4; ++j)
                        acc[i][j] = fmaf(a[i][kk], b[kk][j], acc[i][j]);
        }
    }
    f4 hobs[4];
    {
        f4 bias = *(const f4*)(b1 + cb1 * 4);
        #pragma unroll
        for (int i = 0; i < 4; ++i)
            #pragma unroll
            for (int j = 0; j < 4; ++j)
                hobs[i][j] = acc[i][j] + bias[j];
    }
    __syncthreads();   // prologue LDS dead; safe to overwrite

    // ================= stage persistent weights =================
    // W1 act-part rows 256..287 (4096 floats) and full W2 (8192 floats)
    #pragma unroll
    for (int u = 0; u < 4; ++u)
        *(f4*)(lds + W1S_OFF + u * 1024 + tid * 4) =
            *(const f4*)(W1 + OBSD * H1D + u * 1024 + tid * 4);
    #pragma unroll
    for (int u = 0; u < 8; ++u)
        *(f4*)(lds + W2S_OFF + u * 1024 + tid * 4) =
            *(const f4*)(W2 + u * 1024 + tid * 4);

    f4 bias2 = *(const f4*)(b2v + cb2 * 4);
    f4 bias3 = *(const f4*)(b3v + cb3 * 4);

    // act staging indices (one f4 per thread per eval)
    const int atok = tid >> 3;          // token 0..31
    const int aa   = (tid & 7) * 4;     // act dim
    const int g_at = g0 + atok;
    const int n_at = g_at & (NAG - 1);
    const int bt_at = g_at >> 4;

    f4 pw = {0.f, 0.f, 0.f, 0.f};
    f4 pq = {0.f, 0.f, 0.f, 0.f};

    __syncthreads();

    // ================= eval loop =================
    for (int e = 0; e < NEVAL; ++e) {
        if (e != 1) {
            const float* src;
            if (e == 0) src = actions + g_at * ACTD + aa;
            else        src = cf + (n_at * SCF + (e - 2)) * CFS + bt_at * ACTD + aa;
            *(f4*)(lds + ACT_OFF + atok * 36 + aa) = *(const f4*)src;
        }
        __syncthreads();  // B1: acts visible

        // --- GEMM1: h1 = relu(hobs + act @ W1a) -> Hs ---
        f4 hv[4];
        if (e != 1) {
            float a1c[4][4] = {};
            #pragma unroll
            for (int k0 = 0; k0 < ACTD; k0 += 4) {
                f4 a[4], b[4];
                #pragma unroll
                for (int i = 0; i < 4; ++i)
                    a[i] = *(const f4*)(lds + ACT_OFF + (rb1 * 4 + i) * 36 + k0);
                #pragma unroll
                for (int kk = 0; kk < 4; ++kk)
                    b[kk] = *(const f4*)(lds + W1S_OFF + (k0 + kk) * H1D + cb1 * 4);
                #pragma unroll
                for (int i = 0; i < 4; ++i)
                    #pragma unroll
                    for (int kk = 0; kk < 4; ++kk)
                        #pragma unroll
                        for (int j = 0; j < 4; ++j)
                            a1c[i][j] = fmaf(a[i][kk], b[kk][j], a1c[i][j]);
            }
            #pragma unroll
            for (int i = 0; i < 4; ++i)
                #pragma unroll
                for (int j = 0; j < 4; ++j)
                    hv[i][j] = fmaxf(hobs[i][j] + a1c[i][j], 0.f);
        } else {
            #pragma unroll
            for (int i = 0; i < 4; ++i)
                #pragma unroll
                for (int j = 0; j < 4; ++j)
                    hv[i][j] = fmaxf(hobs[i][j], 0.f);
        }
        #pragma unroll
        for (int i = 0; i < 4; ++i)
            *(f4*)(lds + HS_OFF + (rb1 * 4 + i) * 132 + cb1 * 4) = hv[i];
        __syncthreads();  // B2: Hs visible

        // --- GEMM2: h2 = relu(h1 @ W2 + b2) -> H2s ---
        {
            float acc2[2][4] = {};
            const int t0 = rb2 * 2, t1 = rb2 * 2 + 1;
            #pragma unroll 8
            for (int k0 = 0; k0 < H1D; k0 += 4) {
                f4 a0 = *(const f4*)(lds + HS_OFF + t0 * 132 + k0);
                f4 a1 = *(const f4*)(lds + HS_OFF + t1 * 132 + k0);
                f4 b[4];
                #pragma unroll
                for (int kk = 0; kk < 4; ++kk)
                    b[kk] = *(const f4*)(lds + W2S_OFF + (k0 + kk) * H2D + cb2 * 4);
                #pragma unroll
                for (int kk = 0; kk < 4; ++kk)
                    #pragma unroll
                    for (int j = 0; j < 4; ++j) {
                        acc2[0][j] = fmaf(a0[kk], b[kk][j], acc2[0][j]);
                        acc2[1][j] = fmaf(a1[kk], b[kk][j], acc2[1][j]);
                    }
            }
            f4 v0, v1;
            #pragma unroll
            for (int j = 0; j < 4; ++j) {
                v0[j] = fmaxf(acc2[0][j] + bias2[j], 0.f);
                v1[j] = fmaxf(acc2[1][j] + bias2[j], 0.f);
            }
            *(f4*)(lds + H2S_OFF + t0 * 68 + cb2 * 4) = v0;
            *(f4*)(lds + H2S_OFF + t1 * 68 + cb2 * 4) = v1;
        }
        __syncthreads();  // B3: H2s visible

        // --- GEMM3: p = h2 @ W3 + b3 (W3 via L1) ---
        {
            f4 a3 = {0.f, 0.f, 0.f, 0.f};
            #pragma unroll 8
            for (int k0 = 0; k0 < H2D; k0 += 4) {
                f4 a = *(const f4*)(lds + H2S_OFF + r3 * 68 + k0);
                #pragma unroll
                for (int kk = 0; kk < 4; ++kk) {
                    f4 b = *(const f4*)(W3 + (k0 + kk) * ACTD + cb3 * 4);
                    #pragma unroll
                    for (int j = 0; j < 4; ++j)
                        a3[j] = fmaf(a[kk], b[j], a3[j]);
                }
            }
            #pragma unroll
            for (int j = 0; j < 4; ++j) a3[j] += bias3[j];
            if (e == 0) pw = a3;
            else {
                #pragma unroll
                for (int j = 0; j < 4; ++j) pq[j] += a3[j];
            }
        }
        __syncthreads();  // B4: GEMM3 reads done before next Hs/H2s writes
    }

    // ================= KL epilogue =================
    const float inv17 = 1.0f / 17.0f;
    f4 qv;
    #pragma unroll
    for (int j = 0; j < 4; ++j) qv[j] = pq[j] * inv17;

    float mw = fmaxf(fmaxf(pw[0], pw[1]), fmaxf(pw[2], pw[3]));
    float mq = fmaxf(fmaxf(qv[0], qv[1]), fmaxf(qv[2], qv[3]));
    #pragma unroll
    for (int m = 1; m < 8; m <<= 1) {
        mw = fmaxf(mw, __shfl_xor(mw, m));
        mq = fmaxf(mq, __shfl_xor(mq, m));
    }
    float sw = 0.f, sq = 0.f;
    #pragma unroll
    for (int j = 0; j < 4; ++j) {
        sw += expf(pw[j] - mw);
        sq += expf(qv[j] - mq);
    }
    #pragma unroll
    for (int m = 1; m < 8; m <<= 1) {
        sw += __shfl_xor(sw, m);
        sq += __shfl_xor(sq, m);
    }
    const float lsw = logf(sw), lsq = logf(sq);
    float kl = 0.f;
    #pragma unroll
    for (int j = 0; j < 4; ++j) {
        float lq = qv[j] - mq - lsq;
        float lp = pw[j] - mw - lsw;
        kl += expf(lq) * (lq - lp);
    }
    #pragma unroll
    for (int m = 1; m < 8; m <<= 1) kl += __shfl_xor(kl, m);

    if (cb3 == 0) out[g0 + r3] = kl * (1.0f / 32.0f);
}

// ---------------------------------------------------------------------------
extern "C" void kernel_launch(void* const* d_in, const int* in_sizes, int n_in,
                              void* d_out, int out_size, void* d_ws, size_t ws_size,
                              hipStream_t stream)
{
    const float* obs     = (const float*)d_in[0];
    const float* actions = (const float*)d_in[1];
    const float* cf      = (const float*)d_in[2];
    const float* W1      = (const float*)d_in[3];
    const float* b1      = (const float*)d_in[4];
    const float* W2      = (const float*)d_in[5];
    const float* b2      = (const float*)d_in[6];
    const float* W3      = (const float*)d_in[7];
    const float* b3      = (const float*)d_in[8];
    float* outp = (float*)d_out;

    k_fused<<<NTOK / 32, 256, 0, stream>>>(obs, actions, cf, W1, b1, W2,
                                           b2, W3, b3, outp);
}

// Round 6
// 264.139 us; speedup vs baseline: 1.6448x; 1.0035x over previous
//
#include <hip/hip_runtime.h>

// Problem constants (fixed by reference)
#define NAG   16
#define OBSD  256
#define ACTD  32
#define SCF   16
#define H1D   128
#define H2D   64
#define BT    1024          // B*T
#define NTOK  16384         // BT*NAG
#define NEVAL 18

typedef float f4 __attribute__((ext_vector_type(4)));

// ---- LDS float-offset map (union of prologue / main phases) ----
// prologue: OBS [0,8192) 32x256 ; BS [8192,12288) 32x128
// main:     W1s [0,4096) 32x128 ; W2s [4096,12288) 128x64 ;
//           Hs [12288,16384) 32x128 swizzled ; H2s [16384,18432) 32x64 swizzled
#define OBS_OFF  0
#define BS_OFF   8192
#define W1S_OFF  0
#define W2S_OFF  4096
#define HS_OFF   12288
#define H2S_OFF  16384
#define LDS_FLOATS 18432     // 73728 B -> 2 blocks/CU

// row-dependent XOR swizzles (keep 16B alignment: values are 4-aligned)
#define X1(r) (((r) & 7) << 2)   // Hs  (row stride 128): spreads 4-row col reads
#define X2(r) (((r) & 7) << 3)   // H2s (row stride 64): conflict-free GEMM3 reads

// ---------------------------------------------------------------------------
// Single fused kernel: 32 tokens/block, grid 512. LDS-traffic-minimized:
//  - GEMM1 A-operand (actions/cf) read directly from global (broadcast loads)
//  - GEMM2 split-k: 4tok x 4col x K/2 per thread; partials combined in H2s
//  - Hs/H2s XOR-swizzled (no padding)
// ---------------------------------------------------------------------------
__global__ __launch_bounds__(256, 2) void k_fused(
    const float* __restrict__ obs, const float* __restrict__ actions,
    const float* __restrict__ cf, const float* __restrict__ W1,
    const float* __restrict__ b1, const float* __restrict__ W2,
    const float* __restrict__ b2v, const float* __restrict__ W3,
    const float* __restrict__ b3v, float* __restrict__ out)
{
    __shared__ float lds[LDS_FLOATS];

    const int tid = threadIdx.x;
    const int g0  = blockIdx.x * 32;

    // GEMM1/obs mapping: 4 tok x 4 col
    const int rb1 = tid >> 5, cb1 = tid & 31;
    // GEMM2 split-k mapping: 4 tok x 4 col x k-half
    const int kh = tid >> 7;            // 0/1
    const int rg = (tid >> 4) & 7;      // token group (4 tokens)
    const int cg = tid & 15;            // col group (4 cols)
    // GEMM3 mapping: 1 tok x 4 col
    const int r3 = tid >> 3, cb3 = tid & 7;

    // ================= prologue: obs-GEMM -> hobs regs =================
    {
        const float* src = obs + g0 * OBSD;
        #pragma unroll
        for (int j = 0; j < 8; ++j) {
            int idx = tid + j * 256;
            *(f4*)(lds + OBS_OFF + idx * 4) = *(const f4*)(src + idx * 4);
        }
    }

    float acc[4][4] = {};
    for (int kt = 0; kt < OBSD; kt += 32) {
        __syncthreads();
        const float* wsrc = W1 + kt * H1D;
        #pragma unroll
        for (int u = 0; u < 4; ++u)
            *(f4*)(lds + BS_OFF + u * 1024 + tid * 4) =
                *(const f4*)(wsrc + u * 1024 + tid * 4);
        __syncthreads();
        #pragma unroll
        for (int k0 = 0; k0 < 32; k0 += 4) {
            f4 a[4], b[4];
            #pragma unroll
            for (int i = 0; i < 4; ++i)
                a[i] = *(const f4*)(lds + OBS_OFF + (rb1 * 4 + i) * OBSD + kt + k0);
            #pragma unroll
            for (int kk = 0; kk < 4; ++kk)
                b[kk] = *(const f4*)(lds + BS_OFF + (k0 + kk) * H1D + cb1 * 4);
            #pragma unroll
            for (int i = 0; i < 4; ++i)
                #pragma unroll
                for (int kk = 0; kk < 4; ++kk)
                    #pragma unroll
                    for (int j = 0; j < 4; ++j)
                        acc[i][j] = fmaf(a[i][kk], b[kk][j], acc[i][j]);
        }
    }
    f4 hobs[4];
    {
        f4 bias = *(const f4*)(b1 + cb1 * 4);
        #pragma unroll
        for (int i = 0; i < 4; ++i)
            #pragma unroll
            for (int j = 0; j < 4; ++j)
                hobs[i][j] = acc[i][j] + bias[j];
    }
    __syncthreads();   // prologue LDS dead

    // ================= stage persistent weights =================
    #pragma unroll
    for (int u = 0; u < 4; ++u)
        *(f4*)(lds + W1S_OFF + u * 1024 + tid * 4) =
            *(const f4*)(W1 + OBSD * H1D + u * 1024 + tid * 4);
    #pragma unroll
    for (int u = 0; u < 8; ++u)
        *(f4*)(lds + W2S_OFF + u * 1024 + tid * 4) =
            *(const f4*)(W2 + u * 1024 + tid * 4);

    f4 bias2 = *(const f4*)(b2v + cg * 4);
    f4 bias3 = *(const f4*)(b3v + cb3 * 4);

    // eval-invariant GEMM1-A addressing (4 token-rows, affine in i)
    const int row0 = rb1 * 4;
    const int n0   = row0 & 15;                // cf agent index of row i=0
    const int btt  = (g0 >> 4) + (row0 >> 4);  // cf (b,t) index, same for 4 rows

    f4 pw = {0.f, 0.f, 0.f, 0.f};
    f4 pq = {0.f, 0.f, 0.f, 0.f};

    __syncthreads();

    // ================= eval loop =================
    for (int e = 0; e < NEVAL; ++e) {
        // --- GEMM1: h1 = relu(hobs + act_e @ W1a); A direct from global ---
        f4 hv[4];
        if (e != 1) {
            const float* asrc;
            int astride;
            if (e == 0) { asrc = actions + (g0 + row0) * ACTD; astride = ACTD; }
            else {
                asrc = cf + n0 * (SCF * BT * ACTD) + (e - 2) * (BT * ACTD)
                          + btt * ACTD;
                astride = SCF * BT * ACTD;
            }
            float a1c[4][4] = {};
            #pragma unroll
            for (int k0 = 0; k0 < ACTD; k0 += 4) {
                f4 a[4], b[4];
                #pragma unroll
                for (int i = 0; i < 4; ++i)
                    a[i] = *(const f4*)(asrc + i * astride + k0);
                #pragma unroll
                for (int kk = 0; kk < 4; ++kk)
                    b[kk] = *(const f4*)(lds + W1S_OFF + (k0 + kk) * H1D + cb1 * 4);
                #pragma unroll
                for (int i = 0; i < 4; ++i)
                    #pragma unroll
                    for (int kk = 0; kk < 4; ++kk)
                        #pragma unroll
                        for (int j = 0; j < 4; ++j)
                            a1c[i][j] = fmaf(a[i][kk], b[kk][j], a1c[i][j]);
            }
            #pragma unroll
            for (int i = 0; i < 4; ++i)
                #pragma unroll
                for (int j = 0; j < 4; ++j)
                    hv[i][j] = fmaxf(hobs[i][j] + a1c[i][j], 0.f);
        } else {
            #pragma unroll
            for (int i = 0; i < 4; ++i)
                #pragma unroll
                for (int j = 0; j < 4; ++j)
                    hv[i][j] = fmaxf(hobs[i][j], 0.f);
        }
        #pragma unroll
        for (int i = 0; i < 4; ++i) {
            int r = rb1 * 4 + i;
            *(f4*)(lds + HS_OFF + r * H1D + ((cb1 * 4) ^ X1(r))) = hv[i];
        }
        __syncthreads();  // B_a: Hs visible

        // --- GEMM2 split-k: acc2 = h1[4tok] @ W2[k-half][4col] ---
        float acc2[4][4] = {};
        {
            const int kb = kh * 64;
            #pragma unroll 8
            for (int k0 = 0; k0 < 64; k0 += 4) {
                f4 a[4], b[4];
                #pragma unroll
                for (int i = 0; i < 4; ++i) {
                    int r = rg * 4 + i;
                    a[i] = *(const f4*)(lds + HS_OFF + r * H1D + ((kb + k0) ^ X1(r)));
                }
                #pragma unroll
                for (int kk = 0; kk < 4; ++kk)
                    b[kk] = *(const f4*)(lds + W2S_OFF + (kb + k0 + kk) * H2D + cg * 4);
                #pragma unroll
                for (int i = 0; i < 4; ++i)
                    #pragma unroll
                    for (int kk = 0; kk < 4; ++kk)
                        #pragma unroll
                        for (int j = 0; j < 4; ++j)
                            acc2[i][j] = fmaf(a[i][kk], b[kk][j], acc2[i][j]);
            }
        }
        // kh==1 writes partials into H2s slots
        if (kh) {
            #pragma unroll
            for (int i = 0; i < 4; ++i) {
                int r = rg * 4 + i;
                f4 v = {acc2[i][0], acc2[i][1], acc2[i][2], acc2[i][3]};
                *(f4*)(lds + H2S_OFF + r * H2D + ((cg * 4) ^ X2(r))) = v;
            }
        }
        __syncthreads();  // B_b: partials visible
        // kh==0 combines (same slots -> race-free), adds bias, relu, final h2
        if (!kh) {
            #pragma unroll
            for (int i = 0; i < 4; ++i) {
                int r = rg * 4 + i;
                float* p = lds + H2S_OFF + r * H2D + ((cg * 4) ^ X2(r));
                f4 part = *(const f4*)p;
                f4 v;
                #pragma unroll
                for (int j = 0; j < 4; ++j)
                    v[j] = fmaxf(acc2[i][j] + part[j] + bias2[j], 0.f);
                *(f4*)p = v;
            }
        }
        __syncthreads();  // B_c: H2s final

        // --- GEMM3: p = h2 @ W3 + b3 (W3 via L1/L2) ---
        {
            f4 a3 = {0.f, 0.f, 0.f, 0.f};
            #pragma unroll 8
            for (int k0 = 0; k0 < H2D; k0 += 4) {
                f4 a = *(const f4*)(lds + H2S_OFF + r3 * H2D + (k0 ^ X2(r3)));
                #pragma unroll
                for (int kk = 0; kk < 4; ++kk) {
                    f4 b = *(const f4*)(W3 + (k0 + kk) * ACTD + cb3 * 4);
                    #pragma unroll
                    for (int j = 0; j < 4; ++j)
                        a3[j] = fmaf(a[kk], b[j], a3[j]);
                }
            }
            #pragma unroll
            for (int j = 0; j < 4; ++j) a3[j] += bias3[j];
            if (e == 0) pw = a3;
            else {
                #pragma unroll
                for (int j = 0; j < 4; ++j) pq[j] += a3[j];
            }
        }
        __syncthreads();  // B_d: GEMM3 reads done before next eval's writes
    }

    // ================= KL epilogue =================
    const float inv17 = 1.0f / 17.0f;
    f4 qv;
    #pragma unroll
    for (int j = 0; j < 4; ++j) qv[j] = pq[j] * inv17;

    float mw = fmaxf(fmaxf(pw[0], pw[1]), fmaxf(pw[2], pw[3]));
    float mq = fmaxf(fmaxf(qv[0], qv[1]), fmaxf(qv[2], qv[3]));
    #pragma unroll
    for (int m = 1; m < 8; m <<= 1) {
        mw = fmaxf(mw, __shfl_xor(mw, m));
        mq = fmaxf(mq, __shfl_xor(mq, m));
    }
    float sw = 0.f, sq = 0.f;
    #pragma unroll
    for (int j = 0; j < 4; ++j) {
        sw += expf(pw[j] - mw);
        sq += expf(qv[j] - mq);
    }
    #pragma unroll
    for (int m = 1; m < 8; m <<= 1) {
        sw += __shfl_xor(sw, m);
        sq += __shfl_xor(sq, m);
    }
    const float lsw = logf(sw), lsq = logf(sq);
    float kl = 0.f;
    #pragma unroll
    for (int j = 0; j < 4; ++j) {
        float lq = qv[j] - mq - lsq;
        float lp = pw[j] - mw - lsw;
        kl += expf(lq) * (lq - lp);
    }
    #pragma unroll
    for (int m = 1; m < 8; m <<= 1) kl += __shfl_xor(kl, m);

    if (cb3 == 0) out[g0 + r3] = kl * (1.0f / 32.0f);
}

// ---------------------------------------------------------------------------
extern "C" void kernel_launch(void* const* d_in, const int* in_sizes, int n_in,
                              void* d_out, int out_size, void* d_ws, size_t ws_size,
                              hipStream_t stream)
{
    const float* obs     = (const float*)d_in[0];
    const float* actions = (const float*)d_in[1];
    const float* cf      = (const float*)d_in[2];
    const float* W1      = (const float*)d_in[3];
    const float* b1      = (const float*)d_in[4];
    const float* W2      = (const float*)d_in[5];
    const float* b2      = (const float*)d_in[6];
    const float* W3      = (const float*)d_in[7];
    const float* b3      = (const float*)d_in[8];
    float* outp = (float*)d_out;

    k_fused<<<NTOK / 32, 256, 0, stream>>>(obs, actions, cf, W1, b1, W2,
                                           b2, W3, b3, outp);
}